// Round 1
// baseline (707.177 us; speedup 1.0000x reference)
//
#include <hip/hip_runtime.h>
#include <stdint.h>

#define B_ 32
#define D_ 512
#define P_ 1024   // H*W = 32*32
#define N_ 32768  // B*P
#define K_ 1024

typedef unsigned long long u64;

__device__ __forceinline__ unsigned fkey(float f) {
    unsigned u = __float_as_uint(f);
    return (u & 0x80000000u) ? ~u : (u | 0x80000000u);
}
__device__ __forceinline__ float funkey(unsigned k) {
    unsigned u = (k & 0x80000000u) ? (k & 0x7fffffffu) : ~k;
    return __uint_as_float(u);
}

// ---------------------------------------------------------------- k_init
// ||e_k||^2 per code (one wave per code, tree reduce), zero counts/flagCount
__global__ __launch_bounds__(256) void k_init(const float* __restrict__ emb,
                                              float* __restrict__ enorm,
                                              int* __restrict__ counts,
                                              int* __restrict__ flagCount) {
    int tid = threadIdx.x;
    int gtid = blockIdx.x * 256 + tid;
    if (gtid < K_) counts[gtid] = 0;
    if (gtid == 0) *flagCount = 0;

    int code = blockIdx.x * 4 + (tid >> 6);   // 256 blocks * 4 waves = 1024
    int lane = tid & 63;
    const float4* row = (const float4*)(emb + (size_t)code * D_);
    float4 a = row[lane * 2];
    float4 b = row[lane * 2 + 1];
    float s = a.x * a.x + a.y * a.y + a.z * a.z + a.w * a.w
            + b.x * b.x + b.y * b.y + b.z * b.z + b.w * b.w;
    #pragma unroll
    for (int off = 32; off; off >>= 1) s += __shfl_down(s, off, 64);
    if (lane == 0) enorm[code] = s;
}

// ---------------------------------------------------------------- k_argmin
// 64 tokens x 64-code ktiles x 32-d chunks, fp32, best-2 tracking.
#define GAP_THR 1e-2f

__global__ __launch_bounds__(256) void k_argmin(const float* __restrict__ z,
                                                const float* __restrict__ emb,
                                                const float* __restrict__ enorm,
                                                int* __restrict__ indices,
                                                int* __restrict__ flags,
                                                int* __restrict__ flagCount) {
    __shared__ float Zs[32][64];
    __shared__ float Es[32][68];   // +4 pad: keeps ds_read_b128 16B-aligned, breaks write conflicts
    __shared__ u64 S1[16][64];
    __shared__ u64 S2[16][64];

    const int tid = threadIdx.x;
    const int tx = tid & 15;       // token group (4 tokens each)
    const int ty = tid >> 4;       // code group (4 codes each)
    const int token0 = blockIdx.x * 64;
    const int b = token0 >> 10;
    const int p0 = token0 & 1023;
    const float* zb = z + (size_t)b * (D_ * P_) + p0;

    u64 best1[4], best2[4];
    #pragma unroll
    for (int i = 0; i < 4; ++i) { best1[i] = ~0ULL; best2[i] = ~0ULL; }

    for (int kt = 0; kt < K_ / 64; ++kt) {
        const int code0 = kt * 64;
        float acc[4][4];
        #pragma unroll
        for (int i = 0; i < 4; ++i)
            #pragma unroll
            for (int j = 0; j < 4; ++j) acc[i][j] = 0.f;

        for (int dc = 0; dc < D_ / 32; ++dc) {
            const int d0 = dc * 32;
            // stage Z tile: Zs[d][t], 512 float4, coalesced
            #pragma unroll
            for (int u = 0; u < 2; ++u) {
                int f = tid * 2 + u;
                int row = f >> 4, c4 = f & 15;
                float4 v = *(const float4*)(zb + (size_t)(d0 + row) * P_ + c4 * 4);
                *(float4*)&Zs[row][c4 * 4] = v;
            }
            // stage E tile transposed: Es[d][c]
            #pragma unroll
            for (int u = 0; u < 2; ++u) {
                int f = tid * 2 + u;
                int code = f >> 3, dq = f & 7;
                float4 v = *(const float4*)(emb + (size_t)(code0 + code) * D_ + d0 + dq * 4);
                Es[dq * 4 + 0][code] = v.x;
                Es[dq * 4 + 1][code] = v.y;
                Es[dq * 4 + 2][code] = v.z;
                Es[dq * 4 + 3][code] = v.w;
            }
            __syncthreads();
            #pragma unroll
            for (int d = 0; d < 32; ++d) {
                float4 zv = *(const float4*)&Zs[d][tx * 4];
                float4 ev = *(const float4*)&Es[d][ty * 4];
                acc[0][0] = fmaf(zv.x, ev.x, acc[0][0]);
                acc[0][1] = fmaf(zv.x, ev.y, acc[0][1]);
                acc[0][2] = fmaf(zv.x, ev.z, acc[0][2]);
                acc[0][3] = fmaf(zv.x, ev.w, acc[0][3]);
                acc[1][0] = fmaf(zv.y, ev.x, acc[1][0]);
                acc[1][1] = fmaf(zv.y, ev.y, acc[1][1]);
                acc[1][2] = fmaf(zv.y, ev.z, acc[1][2]);
                acc[1][3] = fmaf(zv.y, ev.w, acc[1][3]);
                acc[2][0] = fmaf(zv.z, ev.x, acc[2][0]);
                acc[2][1] = fmaf(zv.z, ev.y, acc[2][1]);
                acc[2][2] = fmaf(zv.z, ev.z, acc[2][2]);
                acc[2][3] = fmaf(zv.z, ev.w, acc[2][3]);
                acc[3][0] = fmaf(zv.w, ev.x, acc[3][0]);
                acc[3][1] = fmaf(zv.w, ev.y, acc[3][1]);
                acc[3][2] = fmaf(zv.w, ev.z, acc[3][2]);
                acc[3][3] = fmaf(zv.w, ev.w, acc[3][3]);
            }
            __syncthreads();
        }
        // fold ||e||^2 and update per-thread best-2
        #pragma unroll
        for (int j = 0; j < 4; ++j) {
            int c = code0 + ty * 4 + j;
            float en = enorm[c];
            #pragma unroll
            for (int i = 0; i < 4; ++i) {
                float dist = en - 2.f * acc[i][j];
                u64 pk = ((u64)fkey(dist) << 32) | (unsigned)c;
                if (pk < best1[i]) { best2[i] = best1[i]; best1[i] = pk; }
                else if (pk < best2[i]) { best2[i] = pk; }
            }
        }
    }

    // merge best-2 across the 16 code groups (ty) for each token
    #pragma unroll
    for (int i = 0; i < 4; ++i) {
        S1[ty][tx * 4 + i] = best1[i];
        S2[ty][tx * 4 + i] = best2[i];
    }
    __syncthreads();
    for (int st = 8; st >= 1; st >>= 1) {
        if (ty < st) {
            #pragma unroll
            for (int i = 0; i < 4; ++i) {
                int t = tx * 4 + i;
                u64 a1 = S1[ty][t], a2 = S2[ty][t];
                u64 c1 = S1[ty + st][t], c2 = S2[ty + st][t];
                u64 lo = a1 < c1 ? a1 : c1;
                u64 hi = a1 < c1 ? c1 : a1;
                u64 m2 = a2 < c2 ? a2 : c2;
                S1[ty][t] = lo;
                S2[ty][t] = hi < m2 ? hi : m2;
            }
        }
        __syncthreads();
    }
    if (tid < 64) {
        u64 b1 = S1[0][tid], b2 = S2[0][tid];
        int bi = (int)(b1 & 0xffffffffu);
        indices[token0 + tid] = bi;
        float f1 = funkey((unsigned)(b1 >> 32));
        float f2 = funkey((unsigned)(b2 >> 32));
        if (f2 - f1 < GAP_THR) {
            int pos = atomicAdd(flagCount, 1);
            if (pos < N_) flags[pos] = token0 + tid;
        }
    }
}

// ---------------------------------------------------------------- k_repair
// fp64 exact re-argmin over all K for near-tie tokens.
__global__ __launch_bounds__(256) void k_repair(const float* __restrict__ z,
                                                const float* __restrict__ emb,
                                                const int* __restrict__ flags,
                                                const int* __restrict__ flagCount,
                                                int* __restrict__ indices) {
    __shared__ double zl[512];
    __shared__ double rv[256];
    __shared__ int ri[256];
    int tid = threadIdx.x;
    int nf = *flagCount;
    if (nf > N_) nf = N_;
    for (int fi = blockIdx.x; fi < nf; fi += gridDim.x) {
        int t = flags[fi];
        int b = t >> 10, p = t & 1023;
        const float* zb = z + (size_t)b * (D_ * P_) + p;
        __syncthreads();   // protect zl reuse across loop iterations
        for (int d = tid; d < 512; d += 256) zl[d] = (double)zb[(size_t)d * P_];
        __syncthreads();
        double bval = 1e300;
        int bidx = 0;
        for (int c = tid * 4; c < tid * 4 + 4; ++c) {
            const float* e = emb + (size_t)c * D_;
            double s = 0.0;
            for (int d = 0; d < 512; ++d) {
                double ed = (double)e[d];
                s += ed * ed - 2.0 * ed * zl[d];
            }
            if (s < bval) { bval = s; bidx = c; }
        }
        rv[tid] = bval; ri[tid] = bidx;
        __syncthreads();
        for (int st = 128; st; st >>= 1) {
            if (tid < st) {
                if (rv[tid + st] < rv[tid] ||
                    (rv[tid + st] == rv[tid] && ri[tid + st] < ri[tid])) {
                    rv[tid] = rv[tid + st]; ri[tid] = ri[tid + st];
                }
            }
            __syncthreads();
        }
        if (tid == 0) indices[t] = ri[0];
        __syncthreads();
    }
}

// ---------------------------------------------------------------- k_onehot
// 8 rows per block; single-pass zero+one write, float4 coalesced; counts.
__global__ __launch_bounds__(256) void k_onehot(const int* __restrict__ indices,
                                                float* __restrict__ enc,
                                                int* __restrict__ counts) {
    int tid = threadIdx.x;
    int r = blockIdx.x * 8 + (tid >> 5);
    int l = tid & 31;
    int idx = indices[r];
    if (l == 0) atomicAdd(&counts[idx], 1);
    float4* rowp = (float4*)(enc + (size_t)r * K_);
    #pragma unroll
    for (int i = 0; i < 8; ++i) {
        int c4 = i * 32 + l;
        int base = c4 * 4;
        float4 v;
        v.x = (idx == base) ? 1.f : 0.f;
        v.y = (idx == base + 1) ? 1.f : 0.f;
        v.z = (idx == base + 2) ? 1.f : 0.f;
        v.w = (idx == base + 3) ? 1.f : 0.f;
        rowp[c4] = v;
    }
}

// ---------------------------------------------------------------- k_gather
// z_q_out = ze + (e - ze)  (straight-through, same fp ops as ref); loss partials.
__global__ __launch_bounds__(256) void k_gather(const float* __restrict__ z,
                                                const float* __restrict__ emb,
                                                const int* __restrict__ indices,
                                                float* __restrict__ zq,
                                                float* __restrict__ lossp) {
    int tid = threadIdx.x;
    int gid = blockIdx.x * 256 + tid;
    int p4 = gid & 255;
    int rest = gid >> 8;
    int d = rest & 511;
    int b = rest >> 9;
    int p = p4 * 4;
    size_t zoff = (size_t)b * (D_ * P_) + (size_t)d * P_ + p;
    float4 zv = *(const float4*)(z + zoff);
    int nbase = b * P_ + p;
    int i0 = indices[nbase + 0];
    int i1 = indices[nbase + 1];
    int i2 = indices[nbase + 2];
    int i3 = indices[nbase + 3];
    float e0 = emb[(size_t)i0 * D_ + d];
    float e1 = emb[(size_t)i1 * D_ + d];
    float e2 = emb[(size_t)i2 * D_ + d];
    float e3 = emb[(size_t)i3 * D_ + d];
    float d0 = e0 - zv.x;
    float d1 = e1 - zv.y;
    float d2 = e2 - zv.z;
    float d3 = e3 - zv.w;
    float4 o;
    o.x = zv.x + d0; o.y = zv.y + d1; o.z = zv.z + d2; o.w = zv.w + d3;
    *(float4*)(zq + zoff) = o;
    float s = d0 * d0 + d1 * d1 + d2 * d2 + d3 * d3;
    #pragma unroll
    for (int off = 32; off; off >>= 1) s += __shfl_down(s, off, 64);
    __shared__ float wsum[4];
    if ((tid & 63) == 0) wsum[tid >> 6] = s;
    __syncthreads();
    if (tid == 0) lossp[blockIdx.x] = wsum[0] + wsum[1] + wsum[2] + wsum[3];
}

// ---------------------------------------------------------------- k_final
__global__ __launch_bounds__(1024) void k_final(const float* __restrict__ lossp,
                                                const int* __restrict__ counts,
                                                float* __restrict__ out_loss,
                                                float* __restrict__ out_perp) {
    int tid = threadIdx.x;
    float s = 0.f;
    for (int i = tid; i < 16384; i += 1024) s += lossp[i];
    #pragma unroll
    for (int off = 32; off; off >>= 1) s += __shfl_down(s, off, 64);
    __shared__ float red[16];
    if ((tid & 63) == 0) red[tid >> 6] = s;

    float pr = (float)counts[tid] * (1.f / 32768.f);
    float term = pr * logf(pr + 1e-10f);
    #pragma unroll
    for (int off = 32; off; off >>= 1) term += __shfl_down(term, off, 64);
    __shared__ float red2[16];
    if ((tid & 63) == 0) red2[tid >> 6] = term;
    __syncthreads();
    if (tid == 0) {
        float tot = 0.f;
        for (int i = 0; i < 16; ++i) tot += red[i];
        *out_loss = 0.25f * (tot / 16777216.f);
        float t2 = 0.f;
        for (int i = 0; i < 16; ++i) t2 += red2[i];
        *out_perp = expf(-t2);
    }
}

// ---------------------------------------------------------------- launch
extern "C" void kernel_launch(void* const* d_in, const int* in_sizes, int n_in,
                              void* d_out, int out_size, void* d_ws, size_t ws_size,
                              hipStream_t stream) {
    const float* z   = (const float*)d_in[0];   // [32,512,32,32]
    const float* emb = (const float*)d_in[1];   // [1024,512]

    float* zq       = (float*)d_out;            // 16777216
    float* out_loss = zq + 16777216;            // 1
    float* out_perp = zq + 16777217;            // 1
    float* enc      = zq + 16777218;            // 33554432

    char* ws = (char*)d_ws;
    float* enorm   = (float*)ws;                          // 4 KB
    int* counts    = (int*)(ws + 4096);                   // 4 KB
    int* flagCount = (int*)(ws + 8192);                   // 4 B
    int* flags     = (int*)(ws + 12288);                  // 128 KB
    int* indices   = (int*)(ws + 12288 + 131072);         // 128 KB
    float* lossp   = (float*)(ws + 12288 + 262144);       // 64 KB

    k_init<<<256, 256, 0, stream>>>(emb, enorm, counts, flagCount);
    k_argmin<<<512, 256, 0, stream>>>(z, emb, enorm, indices, flags, flagCount);
    k_repair<<<256, 256, 0, stream>>>(z, emb, flags, flagCount, indices);
    k_onehot<<<4096, 256, 0, stream>>>(indices, enc, counts);
    k_gather<<<16384, 256, 0, stream>>>(z, emb, indices, zq, lossp);
    k_final<<<1, 1024, 0, stream>>>(lossp, counts, out_loss, out_perp);
}

// Round 2
// 409.356 us; speedup vs baseline: 1.7275x; 1.7275x over previous
//
#include <hip/hip_runtime.h>
#include <stdint.h>

#define B_ 32
#define D_ 512
#define P_ 1024   // H*W
#define N_ 32768  // B*P
#define K_ 1024

#define GAP_THR 5e-3f
#define DELTA   2.5e-3

typedef unsigned long long u64;
typedef __attribute__((ext_vector_type(8))) short short8;
typedef __attribute__((ext_vector_type(4))) float float4v;

__device__ __forceinline__ unsigned fkey(float f) {
    unsigned u = __float_as_uint(f);
    return (u & 0x80000000u) ? ~u : (u | 0x80000000u);
}
__device__ __forceinline__ float funkey(unsigned k) {
    unsigned u = (k & 0x80000000u) ? (k & 0x7fffffffu) : ~k;
    return __uint_as_float(u);
}
__device__ __forceinline__ unsigned short f2bf(float x) {
    unsigned u = __float_as_uint(x);
    unsigned r = (u + 0x7fffu + ((u >> 16) & 1u)) >> 16;
    return (unsigned short)r;
}
__device__ __forceinline__ float bf2f(unsigned short h) {
    return __uint_as_float(((unsigned)h) << 16);
}

#define GLOAD_LDS16(gsrc, ldst) \
    __builtin_amdgcn_global_load_lds((const __attribute__((address_space(1))) unsigned int*)(const void*)(gsrc), \
                                     (__attribute__((address_space(3))) unsigned int*)(void*)(ldst), 16, 0, 0)

// ------------------------------------------------------------- k_prepE
// emb fp32 -> Ehi/Elo bf16 planes + enorm (fp64-accurate); zero counts/flagCount
__global__ __launch_bounds__(128) void k_prepE(const float* __restrict__ emb,
                                               unsigned short* __restrict__ Ehi,
                                               unsigned short* __restrict__ Elo,
                                               float* __restrict__ enorm,
                                               int* __restrict__ counts,
                                               int* __restrict__ flagCount) {
    int c = blockIdx.x, tid = threadIdx.x;
    if (tid == 0) counts[c] = 0;
    if (tid == 0 && c == 0) *flagCount = 0;
    float4 v = *(const float4*)(emb + (size_t)c * D_ + tid * 4);
    unsigned short h[4], l[4];
    float xs[4] = {v.x, v.y, v.z, v.w};
    double s = 0.0;
    #pragma unroll
    for (int j = 0; j < 4; ++j) {
        h[j] = f2bf(xs[j]);
        l[j] = f2bf(xs[j] - bf2f(h[j]));
        double d = (double)xs[j];
        s += d * d;
    }
    uint2 wh, wl;
    wh.x = (unsigned)h[0] | ((unsigned)h[1] << 16);
    wh.y = (unsigned)h[2] | ((unsigned)h[3] << 16);
    wl.x = (unsigned)l[0] | ((unsigned)l[1] << 16);
    wl.y = (unsigned)l[2] | ((unsigned)l[3] << 16);
    *(uint2*)(Ehi + (size_t)c * D_ + tid * 4) = wh;
    *(uint2*)(Elo + (size_t)c * D_ + tid * 4) = wl;
    #pragma unroll
    for (int off = 32; off; off >>= 1) s += __shfl_down(s, off, 64);
    __shared__ double ws[2];
    if ((tid & 63) == 0) ws[tid >> 6] = s;
    __syncthreads();
    if (tid == 0) enorm[c] = (float)(ws[0] + ws[1]);
}

// ------------------------------------------------------------- k_prep
// z [32,512,1024] fp32 -> Xhi/Xlo bf16 [32768][512] token-major (LDS transpose)
__global__ __launch_bounds__(256) void k_prep(const float* __restrict__ z,
                                              unsigned short* __restrict__ Xhi,
                                              unsigned short* __restrict__ Xlo) {
    __shared__ float Zl[128][67];
    int tid = threadIdx.x;
    int b = blockIdx.x >> 3, pt = blockIdx.x & 7;
    int p0 = pt * 128;
    int t0 = b * P_ + p0;
    const float* zb = z + ((size_t)b * D_) * P_ + p0;

    for (int dc = 0; dc < 8; ++dc) {
        int d0 = dc * 64;
        __syncthreads();
        #pragma unroll
        for (int jj = 0; jj < 8; ++jj) {
            int flat = jj * 256 + tid;
            int d = flat >> 5, p4 = flat & 31;
            float4 v = *(const float4*)(zb + (size_t)(d0 + d) * P_ + p4 * 4);
            Zl[p4 * 4 + 0][d] = v.x;
            Zl[p4 * 4 + 1][d] = v.y;
            Zl[p4 * 4 + 2][d] = v.z;
            Zl[p4 * 4 + 3][d] = v.w;
        }
        __syncthreads();
        int p = tid & 127, plane = tid >> 7;
        unsigned short* out = (plane ? Xlo : Xhi) + (size_t)(t0 + p) * D_ + d0;
        #pragma unroll
        for (int g = 0; g < 8; ++g) {
            unsigned short hh[8];
            #pragma unroll
            for (int j = 0; j < 8; ++j) {
                float x = Zl[p][g * 8 + j];
                unsigned short hi = f2bf(x);
                hh[j] = plane ? f2bf(x - bf2f(hi)) : hi;
            }
            uint4 w;
            w.x = (unsigned)hh[0] | ((unsigned)hh[1] << 16);
            w.y = (unsigned)hh[2] | ((unsigned)hh[3] << 16);
            w.z = (unsigned)hh[4] | ((unsigned)hh[5] << 16);
            w.w = (unsigned)hh[6] | ((unsigned)hh[7] << 16);
            *(uint4*)(out + g * 8) = w;
        }
    }
}

// ------------------------------------------------------------- k_gemm
// D[t][c] = sum_k Xcat[t][k]*Ecat[c][k]  (bf16x2 split, K'=1536), fold enorm,
// per-block best-2 over its 128 codes -> part[t][cb][2] packed u64.
__global__ __launch_bounds__(256) void k_gemm(const unsigned short* __restrict__ Xhi,
                                              const unsigned short* __restrict__ Xlo,
                                              const unsigned short* __restrict__ Ehi,
                                              const unsigned short* __restrict__ Elo,
                                              const float* __restrict__ enorm,
                                              u64* __restrict__ part) {
    __shared__ __align__(16) unsigned short As[2][4096];  // 8KB: 128 rows x 32 k
    __shared__ __align__(16) unsigned short Bs[2][4096];
    const int tid = threadIdx.x;
    const int wave = tid >> 6, lane = tid & 63;
    const int rb = blockIdx.x & 255, cb = blockIdx.x >> 8;  // same-rb siblings 256 apart -> same XCD
    const int t0 = rb * 128, n0 = cb * 128;
    const int wr = wave >> 1, wc = wave & 1;
    const int lr = lane & 15, lg = lane >> 4;

    float4v acc[4][4];
    #pragma unroll
    for (int mi = 0; mi < 4; ++mi)
        #pragma unroll
        for (int ni = 0; ni < 4; ++ni)
            acc[mi][ni] = (float4v){0.f, 0.f, 0.f, 0.f};

    auto stage = [&](int buf, int ks) {
        const unsigned short* Ap = (ks < 32) ? Xhi : Xlo;
        const unsigned short* Bp = ((ks >> 4) == 1) ? Elo : Ehi;
        int k0 = (ks & 15) * 32;
        #pragma unroll
        for (int cc = 0; cc < 2; ++cc) {
            int c = wave * 2 + cc;
            int o = c * 1024 + lane * 16;          // linear dest byte offset
            int r = o >> 6;                        // row
            int c16 = ((o >> 4) & 3) ^ ((r >> 1) & 3);  // inverse-swizzled source slot
            const unsigned short* sa = Ap + (size_t)(t0 + r) * D_ + k0 + c16 * 8;
            const unsigned short* sb = Bp + (size_t)(n0 + r) * D_ + k0 + c16 * 8;
            GLOAD_LDS16(sa, (char*)&As[buf][0] + c * 1024);
            GLOAD_LDS16(sb, (char*)&Bs[buf][0] + c * 1024);
        }
    };

    stage(0, 0);
    __syncthreads();
    for (int ks = 0; ks < 48; ++ks) {
        int cur = ks & 1;
        if (ks + 1 < 48) stage(cur ^ 1, ks + 1);
        short8 af[4], bf[4];
        #pragma unroll
        for (int mi = 0; mi < 4; ++mi) {
            int r = wr * 64 + mi * 16 + lr;
            int byt = r * 64 + ((lg ^ ((r >> 1) & 3)) << 4);
            af[mi] = *(const short8*)((const char*)&As[cur][0] + byt);
        }
        #pragma unroll
        for (int ni = 0; ni < 4; ++ni) {
            int r = wc * 64 + ni * 16 + lr;
            int byt = r * 64 + ((lg ^ ((r >> 1) & 3)) << 4);
            bf[ni] = *(const short8*)((const char*)&Bs[cur][0] + byt);
        }
        #pragma unroll
        for (int mi = 0; mi < 4; ++mi)
            #pragma unroll
            for (int ni = 0; ni < 4; ++ni)
                acc[mi][ni] = __builtin_amdgcn_mfma_f32_16x16x32_bf16(af[mi], bf[ni], acc[mi][ni], 0, 0, 0);
        __syncthreads();
    }

    // epilogue: dist = enorm[c] - 2*dot ; per-row best-2 over 64 cols (this wave)
    float en[4];
    #pragma unroll
    for (int ni = 0; ni < 4; ++ni) en[ni] = enorm[n0 + wc * 64 + ni * 16 + lr];

    #pragma unroll
    for (int mi = 0; mi < 4; ++mi) {
        #pragma unroll
        for (int rr = 0; rr < 4; ++rr) {
            u64 m1 = ~0ULL, m2 = ~0ULL;
            #pragma unroll
            for (int ni = 0; ni < 4; ++ni) {
                int c = n0 + wc * 64 + ni * 16 + lr;
                float dist = en[ni] - 2.f * acc[mi][ni][rr];
                u64 pk = ((u64)fkey(dist) << 32) | (unsigned)c;
                if (pk < m1) { m2 = m1; m1 = pk; }
                else if (pk < m2) { m2 = pk; }
            }
            #pragma unroll
            for (int mask = 1; mask < 16; mask <<= 1) {
                u64 o1 = __shfl_xor(m1, mask, 64);
                u64 o2 = __shfl_xor(m2, mask, 64);
                u64 lo = m1 < o1 ? m1 : o1;
                u64 hi = m1 < o1 ? o1 : m1;
                u64 mm = m2 < o2 ? m2 : o2;
                m1 = lo;
                m2 = hi < mm ? hi : mm;
            }
            if (lr == 0) {
                int t = t0 + wr * 64 + mi * 16 + lg * 4 + rr;
                // wave wc covers cols wc*64..: two sub-results per cb? -> merge via both waves:
                // each (t, cb) written by wc=0 and wc=1 waves at different slots
                part[((size_t)t * 16 + cb * 2 + wc) * 2 + 0] = m1;
                part[((size_t)t * 16 + cb * 2 + wc) * 2 + 1] = m2;
            }
        }
    }
}

// ------------------------------------------------------------- k_merge
__global__ __launch_bounds__(256) void k_merge(const u64* __restrict__ part,
                                               int* __restrict__ indices,
                                               int* __restrict__ idx2,
                                               float* __restrict__ apxd,
                                               int* __restrict__ flags,
                                               int* __restrict__ flagCount) {
    int t = blockIdx.x * 256 + threadIdx.x;
    u64 m1 = ~0ULL, m2 = ~0ULL;
    for (int s = 0; s < 16; ++s) {
        u64 a1 = part[((size_t)t * 16 + s) * 2 + 0];
        u64 a2 = part[((size_t)t * 16 + s) * 2 + 1];
        u64 lo = m1 < a1 ? m1 : a1;
        u64 hi = m1 < a1 ? a1 : m1;
        u64 mm = m2 < a2 ? m2 : a2;
        m1 = lo;
        m2 = hi < mm ? hi : mm;
    }
    indices[t] = (int)(m1 & 0xffffffffu);
    idx2[t]    = (int)(m2 & 0xffffffffu);
    float v1 = funkey((unsigned)(m1 >> 32));
    float v2 = funkey((unsigned)(m2 >> 32));
    apxd[t * 2 + 0] = v1;
    apxd[t * 2 + 1] = v2;
    if (v2 - v1 < GAP_THR) {
        int pos = atomicAdd(flagCount, 1);
        if (pos < N_) flags[pos] = t;
    }
}

// ------------------------------------------------------------- k_spot
// fp64 exact distances of the claimed best-2; mismatch => flag for full repair.
__global__ __launch_bounds__(256) void k_spot(const unsigned short* __restrict__ Xhi,
                                              const unsigned short* __restrict__ Xlo,
                                              const float* __restrict__ emb,
                                              const int* __restrict__ indices,
                                              const int* __restrict__ idx2,
                                              const float* __restrict__ apxd,
                                              int* __restrict__ flags,
                                              int* __restrict__ flagCount) {
    int wave = threadIdx.x >> 6, lane = threadIdx.x & 63;
    int t = blockIdx.x * 4 + wave;
    uint4 hv = *(const uint4*)(Xhi + (size_t)t * D_ + lane * 8);
    uint4 lv = *(const uint4*)(Xlo + (size_t)t * D_ + lane * 8);
    double x[8];
    unsigned hw[4] = {hv.x, hv.y, hv.z, hv.w};
    unsigned lw[4] = {lv.x, lv.y, lv.z, lv.w};
    #pragma unroll
    for (int j = 0; j < 4; ++j) {
        x[2 * j]     = (double)bf2f((unsigned short)(hw[j] & 0xffff)) + (double)bf2f((unsigned short)(lw[j] & 0xffff));
        x[2 * j + 1] = (double)bf2f((unsigned short)(hw[j] >> 16))    + (double)bf2f((unsigned short)(lw[j] >> 16));
    }
    double res[2];
    int cs[2] = {indices[t], idx2[t]};
    #pragma unroll
    for (int s = 0; s < 2; ++s) {
        const float* e = emb + (size_t)cs[s] * D_ + lane * 8;
        double sum = 0.0;
        #pragma unroll
        for (int j = 0; j < 8; ++j) {
            double ed = (double)e[j];
            sum += ed * ed - 2.0 * ed * x[j];
        }
        #pragma unroll
        for (int off = 32; off; off >>= 1) sum += __shfl_down(sum, off, 64);
        res[s] = sum;
    }
    if (lane == 0) {
        bool bad = fabs(res[0] - (double)apxd[t * 2 + 0]) > DELTA ||
                   fabs(res[1] - (double)apxd[t * 2 + 1]) > DELTA ||
                   res[0] > res[1];
        if (bad) {
            int pos = atomicAdd(flagCount, 1);
            if (pos < N_) flags[pos] = t;
        }
    }
}

// ------------------------------------------------------------- k_repair
__global__ __launch_bounds__(256) void k_repair(const float* __restrict__ z,
                                                const float* __restrict__ emb,
                                                const int* __restrict__ flags,
                                                const int* __restrict__ flagCount,
                                                int* __restrict__ indices) {
    __shared__ double zl[512];
    __shared__ double rv[256];
    __shared__ int ri[256];
    int tid = threadIdx.x;
    int nf = *flagCount;
    if (nf > N_) nf = N_;
    for (int fi = blockIdx.x; fi < nf; fi += gridDim.x) {
        int t = flags[fi];
        int b = t >> 10, p = t & 1023;
        const float* zb = z + (size_t)b * (D_ * P_) + p;
        __syncthreads();
        for (int d = tid; d < 512; d += 256) zl[d] = (double)zb[(size_t)d * P_];
        __syncthreads();
        double bval = 1e300;
        int bidx = 0;
        for (int c = tid * 4; c < tid * 4 + 4; ++c) {
            const float* e = emb + (size_t)c * D_;
            double s = 0.0;
            for (int d = 0; d < 512; ++d) {
                double ed = (double)e[d];
                s += ed * ed - 2.0 * ed * zl[d];
            }
            if (s < bval) { bval = s; bidx = c; }
        }
        rv[tid] = bval; ri[tid] = bidx;
        __syncthreads();
        for (int st = 128; st; st >>= 1) {
            if (tid < st) {
                if (rv[tid + st] < rv[tid] ||
                    (rv[tid + st] == rv[tid] && ri[tid + st] < ri[tid])) {
                    rv[tid] = rv[tid + st]; ri[tid] = ri[tid + st];
                }
            }
            __syncthreads();
        }
        if (tid == 0) indices[t] = ri[0];
        __syncthreads();
    }
}

// ------------------------------------------------------------- k_onehot
__global__ __launch_bounds__(256) void k_onehot(const int* __restrict__ indices,
                                                float* __restrict__ enc,
                                                int* __restrict__ counts) {
    int tid = threadIdx.x;
    int r = blockIdx.x * 8 + (tid >> 5);
    int l = tid & 31;
    int idx = indices[r];
    if (l == 0) atomicAdd(&counts[idx], 1);
    float4* rowp = (float4*)(enc + (size_t)r * K_);
    #pragma unroll
    for (int i = 0; i < 8; ++i) {
        int c4 = i * 32 + l;
        int base = c4 * 4;
        float4 v;
        v.x = (idx == base) ? 1.f : 0.f;
        v.y = (idx == base + 1) ? 1.f : 0.f;
        v.z = (idx == base + 2) ? 1.f : 0.f;
        v.w = (idx == base + 3) ? 1.f : 0.f;
        rowp[c4] = v;
    }
}

// ------------------------------------------------------------- k_gather
__global__ __launch_bounds__(256) void k_gather(const float* __restrict__ z,
                                                const float* __restrict__ emb,
                                                const int* __restrict__ indices,
                                                float* __restrict__ zq,
                                                float* __restrict__ lossp) {
    int tid = threadIdx.x;
    int gid = blockIdx.x * 256 + tid;
    int p4 = gid & 255;
    int rest = gid >> 8;
    int d = rest & 511;
    int b = rest >> 9;
    int p = p4 * 4;
    size_t zoff = (size_t)b * (D_ * P_) + (size_t)d * P_ + p;
    float4 zv = *(const float4*)(z + zoff);
    int nbase = b * P_ + p;
    int i0 = indices[nbase + 0];
    int i1 = indices[nbase + 1];
    int i2 = indices[nbase + 2];
    int i3 = indices[nbase + 3];
    float e0 = emb[(size_t)i0 * D_ + d];
    float e1 = emb[(size_t)i1 * D_ + d];
    float e2 = emb[(size_t)i2 * D_ + d];
    float e3 = emb[(size_t)i3 * D_ + d];
    float d0 = e0 - zv.x;
    float d1 = e1 - zv.y;
    float d2 = e2 - zv.z;
    float d3 = e3 - zv.w;
    float4 o;
    o.x = zv.x + d0; o.y = zv.y + d1; o.z = zv.z + d2; o.w = zv.w + d3;
    *(float4*)(zq + zoff) = o;
    float s = d0 * d0 + d1 * d1 + d2 * d2 + d3 * d3;
    #pragma unroll
    for (int off = 32; off; off >>= 1) s += __shfl_down(s, off, 64);
    __shared__ float wsum[4];
    if ((tid & 63) == 0) wsum[tid >> 6] = s;
    __syncthreads();
    if (tid == 0) lossp[blockIdx.x] = wsum[0] + wsum[1] + wsum[2] + wsum[3];
}

// ------------------------------------------------------------- k_final
__global__ __launch_bounds__(1024) void k_final(const float* __restrict__ lossp,
                                                const int* __restrict__ counts,
                                                float* __restrict__ out_loss,
                                                float* __restrict__ out_perp) {
    int tid = threadIdx.x;
    float s = 0.f;
    for (int i = tid; i < 16384; i += 1024) s += lossp[i];
    #pragma unroll
    for (int off = 32; off; off >>= 1) s += __shfl_down(s, off, 64);
    __shared__ float red[16];
    if ((tid & 63) == 0) red[tid >> 6] = s;

    float pr = (float)counts[tid] * (1.f / 32768.f);
    float term = pr * logf(pr + 1e-10f);
    #pragma unroll
    for (int off = 32; off; off >>= 1) term += __shfl_down(term, off, 64);
    __shared__ float red2[16];
    if ((tid & 63) == 0) red2[tid >> 6] = term;
    __syncthreads();
    if (tid == 0) {
        float tot = 0.f;
        for (int i = 0; i < 16; ++i) tot += red[i];
        *out_loss = 0.25f * (tot / 16777216.f);
        float t2 = 0.f;
        for (int i = 0; i < 16; ++i) t2 += red2[i];
        *out_perp = expf(-t2);
    }
}

// ------------------------------------------------------------- launch
extern "C" void kernel_launch(void* const* d_in, const int* in_sizes, int n_in,
                              void* d_out, int out_size, void* d_ws, size_t ws_size,
                              hipStream_t stream) {
    const float* z   = (const float*)d_in[0];   // [32,512,32,32]
    const float* emb = (const float*)d_in[1];   // [1024,512]

    float* zq       = (float*)d_out;            // 16777216
    float* out_loss = zq + 16777216;
    float* out_perp = zq + 16777217;
    float* enc      = zq + 16777218;            // 33554432 floats

    // small scratch in d_ws (same footprint as proven round-1 layout)
    char* ws = (char*)d_ws;
    float* enorm   = (float*)ws;                          // 4 KB
    int* counts    = (int*)(ws + 4096);                   // 4 KB
    int* flagCount = (int*)(ws + 8192);                   // 4 B
    int* flags     = (int*)(ws + 12288);                  // 128 KB
    int* indices   = (int*)(ws + 12288 + 131072);         // 128 KB
    float* lossp   = (float*)(ws + 12288 + 262144);       // 64 KB

    // big scratch carved from the enc region of d_out (consumed before k_onehot
    // overwrites it). 16B-aligned base.
    char* sb = (char*)d_out + 67108880;
    unsigned short* Xhi = (unsigned short*)(sb);                    // 33.5 MB
    unsigned short* Xlo = (unsigned short*)(sb + 33554432);         // 33.5 MB
    unsigned short* EhiP = (unsigned short*)(sb + 67108864);        // 1 MB
    unsigned short* EloP = (unsigned short*)(sb + 68157440);        // 1 MB
    u64* part  = (u64*)(sb + 69206016);                             // 32768*16*2*8 = 8 MB
    float* apxd = (float*)(sb + 77594624);                          // 256 KB
    int* idx2   = (int*)(sb + 77856768);                            // 128 KB

    k_prepE<<<K_, 128, 0, stream>>>(emb, EhiP, EloP, enorm, counts, flagCount);
    k_prep<<<256, 256, 0, stream>>>(z, Xhi, Xlo);
    k_gemm<<<2048, 256, 0, stream>>>(Xhi, Xlo, EhiP, EloP, enorm, part);
    k_merge<<<128, 256, 0, stream>>>(part, indices, idx2, apxd, flags, flagCount);
    k_spot<<<8192, 256, 0, stream>>>(Xhi, Xlo, emb, indices, idx2, apxd, flags, flagCount);
    k_repair<<<256, 256, 0, stream>>>(z, emb, flags, flagCount, indices);
    k_onehot<<<4096, 256, 0, stream>>>(indices, enc, counts);
    k_gather<<<16384, 256, 0, stream>>>(z, emb, indices, zq, lossp);
    k_final<<<1, 1024, 0, stream>>>(lossp, counts, out_loss, out_perp);
}

// Round 3
// 373.736 us; speedup vs baseline: 1.8922x; 1.0953x over previous
//
#include <hip/hip_runtime.h>
#include <stdint.h>

#define B_ 32
#define D_ 512
#define P_ 1024   // H*W
#define N_ 32768  // B*P
#define K_ 1024

#define GAP_THR 5e-3f

typedef unsigned long long u64;
typedef __attribute__((ext_vector_type(8))) short short8;
typedef __attribute__((ext_vector_type(4))) float float4v;

__device__ __forceinline__ unsigned fkey(float f) {
    unsigned u = __float_as_uint(f);
    return (u & 0x80000000u) ? ~u : (u | 0x80000000u);
}
__device__ __forceinline__ float funkey(unsigned k) {
    unsigned u = (k & 0x80000000u) ? (k & 0x7fffffffu) : ~k;
    return __uint_as_float(u);
}
__device__ __forceinline__ unsigned short f2bf(float x) {
    unsigned u = __float_as_uint(x);
    unsigned r = (u + 0x7fffu + ((u >> 16) & 1u)) >> 16;
    return (unsigned short)r;
}
__device__ __forceinline__ float bf2f(unsigned short h) {
    return __uint_as_float(((unsigned)h) << 16);
}

#define GLOAD_LDS16(gsrc, ldst) \
    __builtin_amdgcn_global_load_lds((const __attribute__((address_space(1))) unsigned int*)(const void*)(gsrc), \
                                     (__attribute__((address_space(3))) unsigned int*)(void*)(ldst), 16, 0, 0)

// ------------------------------------------------------------- k_prepE
// emb fp32 -> Ehi/Elo bf16 planes + enorm (fp64-accurate); zero counts/flagCount
__global__ __launch_bounds__(128) void k_prepE(const float* __restrict__ emb,
                                               unsigned short* __restrict__ Ehi,
                                               unsigned short* __restrict__ Elo,
                                               float* __restrict__ enorm,
                                               int* __restrict__ counts,
                                               int* __restrict__ flagCount) {
    int c = blockIdx.x, tid = threadIdx.x;
    if (tid == 0) counts[c] = 0;
    if (tid == 0 && c == 0) *flagCount = 0;
    float4 v = *(const float4*)(emb + (size_t)c * D_ + tid * 4);
    unsigned short h[4], l[4];
    float xs[4] = {v.x, v.y, v.z, v.w};
    double s = 0.0;
    #pragma unroll
    for (int j = 0; j < 4; ++j) {
        h[j] = f2bf(xs[j]);
        l[j] = f2bf(xs[j] - bf2f(h[j]));
        double d = (double)xs[j];
        s += d * d;
    }
    uint2 wh, wl;
    wh.x = (unsigned)h[0] | ((unsigned)h[1] << 16);
    wh.y = (unsigned)h[2] | ((unsigned)h[3] << 16);
    wl.x = (unsigned)l[0] | ((unsigned)l[1] << 16);
    wl.y = (unsigned)l[2] | ((unsigned)l[3] << 16);
    *(uint2*)(Ehi + (size_t)c * D_ + tid * 4) = wh;
    *(uint2*)(Elo + (size_t)c * D_ + tid * 4) = wl;
    #pragma unroll
    for (int off = 32; off; off >>= 1) s += __shfl_down(s, off, 64);
    __shared__ double ws[2];
    if ((tid & 63) == 0) ws[tid >> 6] = s;
    __syncthreads();
    if (tid == 0) enorm[c] = (float)(ws[0] + ws[1]);
}

// ------------------------------------------------------------- k_prep
// z [32,512,1024] fp32 -> Xhi/Xlo bf16 [32768][512] token-major (LDS transpose).
// Writes: lane -> (chunk c = l&7, token p = (l>>3)+g*16): 8x128B contiguous
// segments per wave per g (vs 64x16B scattered before).
__global__ __launch_bounds__(256) void k_prep(const float* __restrict__ z,
                                              unsigned short* __restrict__ Xhi,
                                              unsigned short* __restrict__ Xlo) {
    __shared__ float Zl[128][67];
    int tid = threadIdx.x;
    int b = blockIdx.x >> 3, pt = blockIdx.x & 7;
    int p0 = pt * 128;
    int t0 = b * P_ + p0;
    const float* zb = z + ((size_t)b * D_) * P_ + p0;
    int plane = tid >> 7, l = tid & 127;
    int c = l & 7;

    for (int dc = 0; dc < 8; ++dc) {
        int d0 = dc * 64;
        __syncthreads();
        #pragma unroll
        for (int jj = 0; jj < 8; ++jj) {
            int flat = jj * 256 + tid;
            int d = flat >> 5, p4 = flat & 31;
            float4 v = *(const float4*)(zb + (size_t)(d0 + d) * P_ + p4 * 4);
            Zl[p4 * 4 + 0][d] = v.x;
            Zl[p4 * 4 + 1][d] = v.y;
            Zl[p4 * 4 + 2][d] = v.z;
            Zl[p4 * 4 + 3][d] = v.w;
        }
        __syncthreads();
        unsigned short* out = (plane ? Xlo : Xhi);
        #pragma unroll
        for (int g = 0; g < 8; ++g) {
            int p = (l >> 3) + g * 16;
            unsigned short hh[8];
            #pragma unroll
            for (int j = 0; j < 8; ++j) {
                float x = Zl[p][c * 8 + j];
                unsigned short hi = f2bf(x);
                hh[j] = plane ? f2bf(x - bf2f(hi)) : hi;
            }
            uint4 w;
            w.x = (unsigned)hh[0] | ((unsigned)hh[1] << 16);
            w.y = (unsigned)hh[2] | ((unsigned)hh[3] << 16);
            w.z = (unsigned)hh[4] | ((unsigned)hh[5] << 16);
            w.w = (unsigned)hh[6] | ((unsigned)hh[7] << 16);
            *(uint4*)(out + (size_t)(t0 + p) * D_ + d0 + c * 8) = w;
        }
    }
}

// ------------------------------------------------------------- k_gemm
// TRANSPOSED roles: A = codes (E planes), B = tokens (X planes).
// Output rows = codes, cols = tokens -> per-lane in-register best-2 over 16
// codes + 2 shuffle rounds over 4 lanes. dist = enorm[c] - 2*dot.
__global__ __launch_bounds__(256) void k_gemm(const unsigned short* __restrict__ Xhi,
                                              const unsigned short* __restrict__ Xlo,
                                              const unsigned short* __restrict__ Ehi,
                                              const unsigned short* __restrict__ Elo,
                                              const float* __restrict__ enorm,
                                              u64* __restrict__ part) {
    __shared__ __align__(16) unsigned short As[2][4096];  // codes  128 x 32
    __shared__ __align__(16) unsigned short Bs[2][4096];  // tokens 128 x 32
    const int tid = threadIdx.x;
    const int wave = tid >> 6, lane = tid & 63;
    // T1 chunked swizzle: XCD x gets works x*256..x*256+255 -> each token
    // panel's 8 code-block sharers are consecutive on one XCD.
    const int work = (blockIdx.x & 7) * 256 + (blockIdx.x >> 3);
    const int cb = work & 7, rb = work >> 3;
    const int c0 = cb * 128, t0 = rb * 128;
    const int wr = wave >> 1, wc = wave & 1;   // wr: code half, wc: token half
    const int lr = lane & 15, lg = lane >> 4;

    float4v acc[4][4];
    #pragma unroll
    for (int mi = 0; mi < 4; ++mi)
        #pragma unroll
        for (int ni = 0; ni < 4; ++ni)
            acc[mi][ni] = (float4v){0.f, 0.f, 0.f, 0.f};

    auto stage = [&](int buf, int ks) {
        const unsigned short* Ap = ((ks >> 4) == 1) ? Elo : Ehi;   // codes
        const unsigned short* Bp = (ks < 32) ? Xhi : Xlo;          // tokens
        int k0 = (ks & 15) * 32;
        #pragma unroll
        for (int cc = 0; cc < 2; ++cc) {
            int c = wave * 2 + cc;
            int o = c * 1024 + lane * 16;               // linear dest byte offset
            int r = o >> 6;                             // row
            int c16 = ((o >> 4) & 3) ^ ((r >> 1) & 3);  // inverse-swizzled src slot
            GLOAD_LDS16(Ap + (size_t)(c0 + r) * D_ + k0 + c16 * 8, (char*)&As[buf][0] + c * 1024);
            GLOAD_LDS16(Bp + (size_t)(t0 + r) * D_ + k0 + c16 * 8, (char*)&Bs[buf][0] + c * 1024);
        }
    };

    stage(0, 0);
    __syncthreads();
    for (int ks = 0; ks < 48; ++ks) {
        int cur = ks & 1;
        if (ks + 1 < 48) stage(cur ^ 1, ks + 1);
        short8 af[4], bf[4];
        #pragma unroll
        for (int mi = 0; mi < 4; ++mi) {
            int r = wr * 64 + mi * 16 + lr;
            int byt = r * 64 + ((lg ^ ((r >> 1) & 3)) << 4);
            af[mi] = *(const short8*)((const char*)&As[cur][0] + byt);
        }
        #pragma unroll
        for (int ni = 0; ni < 4; ++ni) {
            int r = wc * 64 + ni * 16 + lr;
            int byt = r * 64 + ((lg ^ ((r >> 1) & 3)) << 4);
            bf[ni] = *(const short8*)((const char*)&Bs[cur][0] + byt);
        }
        #pragma unroll
        for (int mi = 0; mi < 4; ++mi)
            #pragma unroll
            for (int ni = 0; ni < 4; ++ni)
                acc[mi][ni] = __builtin_amdgcn_mfma_f32_16x16x32_bf16(af[mi], bf[ni], acc[mi][ni], 0, 0, 0);
        __syncthreads();
    }

    // epilogue: lane holds codes {c0+wr*64+mi*16+lg*4+rr} for tokens {wc*64+ni*16+lr}
    float en[4][4];
    #pragma unroll
    for (int mi = 0; mi < 4; ++mi)
        #pragma unroll
        for (int rr = 0; rr < 4; ++rr)
            en[mi][rr] = enorm[c0 + wr * 64 + mi * 16 + lg * 4 + rr];

    #pragma unroll
    for (int ni = 0; ni < 4; ++ni) {
        float v1 = 3.4e38f, v2 = 3.4e38f;
        int c1 = 0;
        #pragma unroll
        for (int mi = 0; mi < 4; ++mi) {
            #pragma unroll
            for (int rr = 0; rr < 4; ++rr) {
                float dist = fmaf(-2.f, acc[mi][ni][rr], en[mi][rr]);
                int code = c0 + wr * 64 + mi * 16 + lg * 4 + rr;
                // ascending code order: strict < keeps lowest code on exact tie
                if (dist < v1) { v2 = v1; v1 = dist; c1 = code; }
                else v2 = fminf(v2, dist);
            }
        }
        #pragma unroll
        for (int mask = 16; mask <= 32; mask <<= 1) {
            float ov1 = __shfl_xor(v1, mask, 64);
            int   oc1 = __shfl_xor(c1, mask, 64);
            float ov2 = __shfl_xor(v2, mask, 64);
            bool take = (ov1 < v1) || (ov1 == v1 && oc1 < c1);
            float loser = take ? v1 : ov1;
            v2 = fminf(fminf(v2, ov2), loser);
            if (take) { v1 = ov1; c1 = oc1; }
        }
        if (lg == 0) {
            int t = t0 + wc * 64 + ni * 16 + lr;
            ulonglong2 pk;
            pk.x = ((u64)fkey(v1) << 32) | (unsigned)c1;
            pk.y = ((u64)fkey(v2) << 32);
            *(ulonglong2*)&part[((size_t)t * 16 + cb * 2 + wr) * 2] = pk;
        }
    }
}

// ------------------------------------------------------------- k_merge
__global__ __launch_bounds__(256) void k_merge(const u64* __restrict__ part,
                                               int* __restrict__ indices,
                                               int* __restrict__ flags,
                                               int* __restrict__ flagCount) {
    int t = blockIdx.x * 256 + threadIdx.x;
    ulonglong2 a0 = *(const ulonglong2*)&part[(size_t)t * 32];
    u64 m1 = a0.x;
    float m2v = funkey((unsigned)(a0.y >> 32));
    for (int s = 1; s < 16; ++s) {
        ulonglong2 a = *(const ulonglong2*)&part[((size_t)t * 16 + s) * 2];
        float ax = funkey((unsigned)(a.x >> 32));
        float ay = funkey((unsigned)(a.y >> 32));
        if (a.x < m1) { m2v = fminf(m2v, funkey((unsigned)(m1 >> 32))); m1 = a.x; }
        else m2v = fminf(m2v, ax);
        m2v = fminf(m2v, ay);
    }
    indices[t] = (int)(m1 & 0xffffffffu);
    float v1 = funkey((unsigned)(m1 >> 32));
    if (m2v - v1 < GAP_THR) {
        int pos = atomicAdd(flagCount, 1);
        if (pos < N_) flags[pos] = t;
    }
}

// ------------------------------------------------------------- k_repair
// fp64 exact re-argmin over all K for near-tie tokens.
__global__ __launch_bounds__(256) void k_repair(const float* __restrict__ z,
                                                const float* __restrict__ emb,
                                                const int* __restrict__ flags,
                                                const int* __restrict__ flagCount,
                                                int* __restrict__ indices) {
    __shared__ double zl[512];
    __shared__ double rv[256];
    __shared__ int ri[256];
    int tid = threadIdx.x;
    int nf = *flagCount;
    if (nf > N_) nf = N_;
    for (int fi = blockIdx.x; fi < nf; fi += gridDim.x) {
        int t = flags[fi];
        int b = t >> 10, p = t & 1023;
        const float* zb = z + (size_t)b * (D_ * P_) + p;
        __syncthreads();
        for (int d = tid; d < 512; d += 256) zl[d] = (double)zb[(size_t)d * P_];
        __syncthreads();
        double bval = 1e300;
        int bidx = 0;
        for (int c = tid * 4; c < tid * 4 + 4; ++c) {
            const float* e = emb + (size_t)c * D_;
            double s = 0.0;
            for (int d = 0; d < 512; ++d) {
                double ed = (double)e[d];
                s += ed * ed - 2.0 * ed * zl[d];
            }
            if (s < bval) { bval = s; bidx = c; }
        }
        rv[tid] = bval; ri[tid] = bidx;
        __syncthreads();
        for (int st = 128; st; st >>= 1) {
            if (tid < st) {
                if (rv[tid + st] < rv[tid] ||
                    (rv[tid + st] == rv[tid] && ri[tid + st] < ri[tid])) {
                    rv[tid] = rv[tid + st]; ri[tid] = ri[tid + st];
                }
            }
            __syncthreads();
        }
        if (tid == 0) indices[t] = ri[0];
        __syncthreads();
    }
}

// ------------------------------------------------------------- k_onehot
__global__ __launch_bounds__(256) void k_onehot(const int* __restrict__ indices,
                                                float* __restrict__ enc,
                                                int* __restrict__ counts) {
    int tid = threadIdx.x;
    int r = blockIdx.x * 8 + (tid >> 5);
    int l = tid & 31;
    int idx = indices[r];
    if (l == 0) atomicAdd(&counts[idx], 1);
    float4* rowp = (float4*)(enc + (size_t)r * K_);
    #pragma unroll
    for (int i = 0; i < 8; ++i) {
        int c4 = i * 32 + l;
        int base = c4 * 4;
        float4 v;
        v.x = (idx == base) ? 1.f : 0.f;
        v.y = (idx == base + 1) ? 1.f : 0.f;
        v.z = (idx == base + 2) ? 1.f : 0.f;
        v.w = (idx == base + 3) ? 1.f : 0.f;
        rowp[c4] = v;
    }
}

// ------------------------------------------------------------- k_gather
__global__ __launch_bounds__(256) void k_gather(const float* __restrict__ z,
                                                const float* __restrict__ emb,
                                                const int* __restrict__ indices,
                                                float* __restrict__ zq,
                                                float* __restrict__ lossp) {
    int tid = threadIdx.x;
    int gid = blockIdx.x * 256 + tid;
    int p4 = gid & 255;
    int rest = gid >> 8;
    int d = rest & 511;
    int b = rest >> 9;
    int p = p4 * 4;
    size_t zoff = (size_t)b * (D_ * P_) + (size_t)d * P_ + p;
    float4 zv = *(const float4*)(z + zoff);
    int nbase = b * P_ + p;
    int i0 = indices[nbase + 0];
    int i1 = indices[nbase + 1];
    int i2 = indices[nbase + 2];
    int i3 = indices[nbase + 3];
    float e0 = emb[(size_t)i0 * D_ + d];
    float e1 = emb[(size_t)i1 * D_ + d];
    float e2 = emb[(size_t)i2 * D_ + d];
    float e3 = emb[(size_t)i3 * D_ + d];
    float d0 = e0 - zv.x;
    float d1 = e1 - zv.y;
    float d2 = e2 - zv.z;
    float d3 = e3 - zv.w;
    float4 o;
    o.x = zv.x + d0; o.y = zv.y + d1; o.z = zv.z + d2; o.w = zv.w + d3;
    *(float4*)(zq + zoff) = o;
    float s = d0 * d0 + d1 * d1 + d2 * d2 + d3 * d3;
    #pragma unroll
    for (int off = 32; off; off >>= 1) s += __shfl_down(s, off, 64);
    __shared__ float wsum[4];
    if ((tid & 63) == 0) wsum[tid >> 6] = s;
    __syncthreads();
    if (tid == 0) lossp[blockIdx.x] = wsum[0] + wsum[1] + wsum[2] + wsum[3];
}

// ------------------------------------------------------------- k_final
__global__ __launch_bounds__(1024) void k_final(const float* __restrict__ lossp,
                                                const int* __restrict__ counts,
                                                float* __restrict__ out_loss,
                                                float* __restrict__ out_perp) {
    int tid = threadIdx.x;
    float s = 0.f;
    for (int i = tid; i < 16384; i += 1024) s += lossp[i];
    #pragma unroll
    for (int off = 32; off; off >>= 1) s += __shfl_down(s, off, 64);
    __shared__ float red[16];
    if ((tid & 63) == 0) red[tid >> 6] = s;

    float pr = (float)counts[tid] * (1.f / 32768.f);
    float term = pr * logf(pr + 1e-10f);
    #pragma unroll
    for (int off = 32; off; off >>= 1) term += __shfl_down(term, off, 64);
    __shared__ float red2[16];
    if ((tid & 63) == 0) red2[tid >> 6] = term;
    __syncthreads();
    if (tid == 0) {
        float tot = 0.f;
        for (int i = 0; i < 16; ++i) tot += red[i];
        *out_loss = 0.25f * (tot / 16777216.f);
        float t2 = 0.f;
        for (int i = 0; i < 16; ++i) t2 += red2[i];
        *out_perp = expf(-t2);
    }
}

// ------------------------------------------------------------- launch
extern "C" void kernel_launch(void* const* d_in, const int* in_sizes, int n_in,
                              void* d_out, int out_size, void* d_ws, size_t ws_size,
                              hipStream_t stream) {
    const float* z   = (const float*)d_in[0];   // [32,512,32,32]
    const float* emb = (const float*)d_in[1];   // [1024,512]

    float* zq       = (float*)d_out;            // 16777216
    float* out_loss = zq + 16777216;
    float* out_perp = zq + 16777217;
    float* enc      = zq + 16777218;            // 33554432 floats

    // small scratch in d_ws
    char* ws = (char*)d_ws;
    float* enorm   = (float*)ws;                          // 4 KB
    int* counts    = (int*)(ws + 4096);                   // 4 KB
    int* flagCount = (int*)(ws + 8192);                   // 4 B
    int* flags     = (int*)(ws + 12288);                  // 128 KB
    int* indices   = (int*)(ws + 12288 + 131072);         // 128 KB
    float* lossp   = (float*)(ws + 12288 + 262144);       // 64 KB

    // big scratch carved from the enc region of d_out (fully consumed before
    // k_onehot overwrites it; rewritten every call -> deterministic).
    char* sb = (char*)d_out + 67108880;
    unsigned short* Xhi  = (unsigned short*)(sb);                   // 33.5 MB
    unsigned short* Xlo  = (unsigned short*)(sb + 33554432);        // 33.5 MB
    unsigned short* EhiP = (unsigned short*)(sb + 67108864);        // 1 MB
    unsigned short* EloP = (unsigned short*)(sb + 68157440);        // 1 MB
    u64* part = (u64*)(sb + 69206016);                              // 8 MB

    k_prepE<<<K_, 128, 0, stream>>>(emb, EhiP, EloP, enorm, counts, flagCount);
    k_prep<<<256, 256, 0, stream>>>(z, Xhi, Xlo);
    k_gemm<<<2048, 256, 0, stream>>>(Xhi, Xlo, EhiP, EloP, enorm, part);
    k_merge<<<128, 256, 0, stream>>>(part, indices, flags, flagCount);
    k_repair<<<256, 256, 0, stream>>>(z, emb, flags, flagCount, indices);
    k_onehot<<<4096, 256, 0, stream>>>(indices, enc, counts);
    k_gather<<<16384, 256, 0, stream>>>(z, emb, indices, zq, lossp);
    k_final<<<1, 1024, 0, stream>>>(lossp, counts, out_loss, out_perp);
}

// Round 4
// 306.289 us; speedup vs baseline: 2.3089x; 1.2202x over previous
//
#include <hip/hip_runtime.h>
#include <stdint.h>

#define B_ 32
#define D_ 512
#define P_ 1024   // H*W
#define N_ 32768  // B*P
#define K_ 1024

#define GAP_THR 5e-3f

typedef unsigned long long u64;
typedef __attribute__((ext_vector_type(8))) short short8;
typedef __attribute__((ext_vector_type(4))) float float4v;

__device__ __forceinline__ unsigned fkey(float f) {
    unsigned u = __float_as_uint(f);
    return (u & 0x80000000u) ? ~u : (u | 0x80000000u);
}
__device__ __forceinline__ float funkey(unsigned k) {
    unsigned u = (k & 0x80000000u) ? (k & 0x7fffffffu) : ~k;
    return __uint_as_float(u);
}
__device__ __forceinline__ unsigned short f2bf(float x) {
    unsigned u = __float_as_uint(x);
    unsigned r = (u + 0x7fffu + ((u >> 16) & 1u)) >> 16;
    return (unsigned short)r;
}
__device__ __forceinline__ float bf2f(unsigned short h) {
    return __uint_as_float(((unsigned)h) << 16);
}

#define GLOAD_LDS16(gsrc, ldst) \
    __builtin_amdgcn_global_load_lds((const __attribute__((address_space(1))) unsigned int*)(const void*)(gsrc), \
                                     (__attribute__((address_space(3))) unsigned int*)(void*)(ldst), 16, 0, 0)

// ------------------------------------------------------------- k_prepE
__global__ __launch_bounds__(128) void k_prepE(const float* __restrict__ emb,
                                               unsigned short* __restrict__ Ehi,
                                               unsigned short* __restrict__ Elo,
                                               float* __restrict__ enorm,
                                               int* __restrict__ counts,
                                               int* __restrict__ flagCount) {
    int c = blockIdx.x, tid = threadIdx.x;
    if (tid == 0) counts[c] = 0;
    if (tid == 0 && c == 0) *flagCount = 0;
    float4 v = *(const float4*)(emb + (size_t)c * D_ + tid * 4);
    unsigned short h[4], l[4];
    float xs[4] = {v.x, v.y, v.z, v.w};
    double s = 0.0;
    #pragma unroll
    for (int j = 0; j < 4; ++j) {
        h[j] = f2bf(xs[j]);
        l[j] = f2bf(xs[j] - bf2f(h[j]));
        double d = (double)xs[j];
        s += d * d;
    }
    uint2 wh, wl;
    wh.x = (unsigned)h[0] | ((unsigned)h[1] << 16);
    wh.y = (unsigned)h[2] | ((unsigned)h[3] << 16);
    wl.x = (unsigned)l[0] | ((unsigned)l[1] << 16);
    wl.y = (unsigned)l[2] | ((unsigned)l[3] << 16);
    *(uint2*)(Ehi + (size_t)c * D_ + tid * 4) = wh;
    *(uint2*)(Elo + (size_t)c * D_ + tid * 4) = wl;
    #pragma unroll
    for (int off = 32; off; off >>= 1) s += __shfl_down(s, off, 64);
    __shared__ double ws[2];
    if ((tid & 63) == 0) ws[tid >> 6] = s;
    __syncthreads();
    if (tid == 0) enorm[c] = (float)(ws[0] + ws[1]);
}

// ------------------------------------------------------------- k_prep
__global__ __launch_bounds__(256) void k_prep(const float* __restrict__ z,
                                              unsigned short* __restrict__ Xhi,
                                              unsigned short* __restrict__ Xlo) {
    __shared__ float Zl[128][67];
    int tid = threadIdx.x;
    int b = blockIdx.x >> 3, pt = blockIdx.x & 7;
    int p0 = pt * 128;
    int t0 = b * P_ + p0;
    const float* zb = z + ((size_t)b * D_) * P_ + p0;
    int plane = tid >> 7, l = tid & 127;
    int c = l & 7;

    for (int dc = 0; dc < 8; ++dc) {
        int d0 = dc * 64;
        __syncthreads();
        #pragma unroll
        for (int jj = 0; jj < 8; ++jj) {
            int flat = jj * 256 + tid;
            int d = flat >> 5, p4 = flat & 31;
            float4 v = *(const float4*)(zb + (size_t)(d0 + d) * P_ + p4 * 4);
            Zl[p4 * 4 + 0][d] = v.x;
            Zl[p4 * 4 + 1][d] = v.y;
            Zl[p4 * 4 + 2][d] = v.z;
            Zl[p4 * 4 + 3][d] = v.w;
        }
        __syncthreads();
        unsigned short* out = (plane ? Xlo : Xhi);
        #pragma unroll
        for (int g = 0; g < 8; ++g) {
            int p = (l >> 3) + g * 16;
            unsigned short hh[8];
            #pragma unroll
            for (int j = 0; j < 8; ++j) {
                float x = Zl[p][c * 8 + j];
                unsigned short hi = f2bf(x);
                hh[j] = plane ? f2bf(x - bf2f(hi)) : hi;
            }
            uint4 w;
            w.x = (unsigned)hh[0] | ((unsigned)hh[1] << 16);
            w.y = (unsigned)hh[2] | ((unsigned)hh[3] << 16);
            w.z = (unsigned)hh[4] | ((unsigned)hh[5] << 16);
            w.w = (unsigned)hh[6] | ((unsigned)hh[7] << 16);
            *(uint4*)(out + (size_t)(t0 + p) * D_ + d0 + c * 8) = w;
        }
    }
}

// ------------------------------------------------------------- k_gemm
// 256x256 tile, BK=64, 8 waves (2 code-halves x 4 token-quarters), 8-phase
// style schedule with counted vmcnt, raw s_barrier, setprio. A=codes, B=tokens.
// K'=1536 = 3 segs x 8 tiles: seg0 Ehi*Xhi, seg1 Elo*Xhi, seg2 Ehi*Xlo.
__global__ __launch_bounds__(512, 2) void k_gemm(const unsigned short* __restrict__ Xhi,
                                                 const unsigned short* __restrict__ Xlo,
                                                 const unsigned short* __restrict__ Ehi,
                                                 const unsigned short* __restrict__ Elo,
                                                 const float* __restrict__ enorm,
                                                 u64* __restrict__ part) {
    // LDS: buf(2) x {A,B} x khalf(2) x 16KB = 128 KiB
    __shared__ __align__(16) char smem[131072];
    const int tid = threadIdx.x;
    const int wave = tid >> 6, lane = tid & 63;
    const int lr = lane & 15, lg = lane >> 4;
    const int wr = wave >> 2, wc = wave & 3;   // wr: code half, wc: token quarter
    // XCD swizzle: 512 blocks, XCD x owns works x*64..x*64+63 (16 rb panels x 4 cb)
    const int work = (blockIdx.x & 7) * 64 + (blockIdx.x >> 3);
    const int rb = work >> 2, cb = work & 3;
    const int t0 = rb * 256, c0 = cb * 256;

    float4v acc[8][4];
    #pragma unroll
    for (int i = 0; i < 8; ++i)
        #pragma unroll
        for (int j = 0; j < 4; ++j)
            acc[i][j] = (float4v){0.f, 0.f, 0.f, 0.f};

    // stage half-tile h: tile T=h>>2, j=h&3 (0=A-k0, 1=B-k0, 2=A-k1, 3=B-k1)
    auto stageHalf = [&](int h) {
        if (h >= 96) return;
        int T = h >> 2, j = h & 3;
        int khalf = j >> 1;
        int isB = j & 1;
        const unsigned short* plane;
        int row0;
        if (!isB) { plane = (T >= 8 && T < 16) ? Elo : Ehi; row0 = c0; }
        else      { plane = (T < 16) ? Xhi : Xlo;           row0 = t0; }
        int kseg = (T & 7) * 64 + khalf * 32;
        char* region = smem + (T & 1) * 65536 + isB * 32768 + khalf * 16384;
        #pragma unroll
        for (int jj = 0; jj < 2; ++jj) {
            int o = jj * 8192 + wave * 1024 + lane * 16;
            int pair = o >> 7;
            int sl = ((o >> 4) & 7) ^ (pair & 7);
            int row = pair * 2 + (sl >> 2);
            int k8 = sl & 3;
            GLOAD_LDS16(plane + (size_t)(row0 + row) * D_ + kseg + k8 * 8,
                        region + jj * 8192 + wave * 1024);
        }
    };

    // prologue: stage halves 0..5 (tiles 0 + half of 1)
    for (int h = 0; h < 6; ++h) stageHalf(h);

    for (int t = 0; t < 24; ++t) {
        const int buf = t & 1;
        const char* Ab = smem + buf * 65536;
        const char* Bb = smem + buf * 65536 + 32768;
        // gate: tile t's 4 halves complete; 2 newer halves (4 loads) in flight
        if (t < 23) { asm volatile("s_waitcnt vmcnt(4)" ::: "memory"); }
        else        { asm volatile("s_waitcnt vmcnt(0)" ::: "memory"); }
        __builtin_amdgcn_s_barrier();
        __builtin_amdgcn_sched_barrier(0);
        #pragma unroll
        for (int q = 0; q < 4; ++q) {
            const int ks = q >> 1, mq = q & 1;
            const char* Ar = Ab + ks * 16384;
            const char* Br = Bb + ks * 16384;
            short8 af[4], bf[4];
            #pragma unroll
            for (int i = 0; i < 4; ++i) {
                int arow = wr * 128 + (mq * 4 + i) * 16 + lr;
                int ap = arow >> 1;
                int as_ = (((arow & 1) << 2) | lg) ^ (ap & 7);
                af[i] = *(const short8*)(Ar + ap * 128 + as_ * 16);
            }
            #pragma unroll
            for (int i = 0; i < 4; ++i) {
                int brow = wc * 64 + i * 16 + lr;
                int bp = brow >> 1;
                int bs_ = (((brow & 1) << 2) | lg) ^ (bp & 7);
                bf[i] = *(const short8*)(Br + bp * 128 + bs_ * 16);
            }
            stageHalf(4 * t + q + 6);
            __builtin_amdgcn_sched_barrier(0);
            __builtin_amdgcn_s_barrier();
            asm volatile("s_waitcnt lgkmcnt(0)" ::: "memory");
            __builtin_amdgcn_sched_barrier(0);
            __builtin_amdgcn_s_setprio(1);
            #pragma unroll
            for (int i = 0; i < 4; ++i)
                #pragma unroll
                for (int j = 0; j < 4; ++j)
                    acc[mq * 4 + i][j] = __builtin_amdgcn_mfma_f32_16x16x32_bf16(af[i], bf[j], acc[mq * 4 + i][j], 0, 0, 0);
            __builtin_amdgcn_s_setprio(0);
            __builtin_amdgcn_s_barrier();
        }
    }

    // epilogue: lane holds codes {c0+wr*128+mi*16+lg*4+rr} for tokens
    // {t0+wc*64+ni*16+lr}; best-2 over 32 in-reg codes + lg-group shuffles.
    float en[8][4];
    #pragma unroll
    for (int mi = 0; mi < 8; ++mi)
        #pragma unroll
        for (int rr = 0; rr < 4; ++rr)
            en[mi][rr] = enorm[c0 + wr * 128 + mi * 16 + lg * 4 + rr];

    #pragma unroll
    for (int ni = 0; ni < 4; ++ni) {
        float v1 = 3.4e38f, v2 = 3.4e38f;
        int c1 = 0;
        #pragma unroll
        for (int mi = 0; mi < 8; ++mi) {
            #pragma unroll
            for (int rr = 0; rr < 4; ++rr) {
                float dist = fmaf(-2.f, acc[mi][ni][rr], en[mi][rr]);
                int code = c0 + wr * 128 + mi * 16 + lg * 4 + rr;
                if (dist < v1) { v2 = v1; v1 = dist; c1 = code; }
                else v2 = fminf(v2, dist);
            }
        }
        #pragma unroll
        for (int mask = 16; mask <= 32; mask <<= 1) {
            float ov1 = __shfl_xor(v1, mask, 64);
            int   oc1 = __shfl_xor(c1, mask, 64);
            float ov2 = __shfl_xor(v2, mask, 64);
            bool take = (ov1 < v1) || (ov1 == v1 && oc1 < c1);
            float loser = take ? v1 : ov1;
            v2 = fminf(fminf(v2, ov2), loser);
            if (take) { v1 = ov1; c1 = oc1; }
        }
        if (lg == 0) {
            int t = t0 + wc * 64 + ni * 16 + lr;
            ulonglong2 pk;
            pk.x = ((u64)fkey(v1) << 32) | (unsigned)c1;
            pk.y = ((u64)fkey(v2) << 32);
            *(ulonglong2*)&part[((size_t)t * 8 + cb * 2 + wr) * 2] = pk;
        }
    }
}

// ------------------------------------------------------------- k_merge
__global__ __launch_bounds__(256) void k_merge(const u64* __restrict__ part,
                                               int* __restrict__ indices,
                                               int* __restrict__ flags,
                                               int* __restrict__ flagCount) {
    int t = blockIdx.x * 256 + threadIdx.x;
    ulonglong2 a0 = *(const ulonglong2*)&part[(size_t)t * 16];
    u64 m1 = a0.x;
    float m2v = funkey((unsigned)(a0.y >> 32));
    for (int s = 1; s < 8; ++s) {
        ulonglong2 a = *(const ulonglong2*)&part[((size_t)t * 8 + s) * 2];
        float ax = funkey((unsigned)(a.x >> 32));
        float ay = funkey((unsigned)(a.y >> 32));
        if (a.x < m1) { m2v = fminf(m2v, funkey((unsigned)(m1 >> 32))); m1 = a.x; }
        else m2v = fminf(m2v, ax);
        m2v = fminf(m2v, ay);
    }
    indices[t] = (int)(m1 & 0xffffffffu);
    float v1 = funkey((unsigned)(m1 >> 32));
    if (m2v - v1 < GAP_THR) {
        int pos = atomicAdd(flagCount, 1);
        if (pos < N_) flags[pos] = t;
    }
}

// ------------------------------------------------------------- k_repair
__global__ __launch_bounds__(256) void k_repair(const float* __restrict__ z,
                                                const float* __restrict__ emb,
                                                const int* __restrict__ flags,
                                                const int* __restrict__ flagCount,
                                                int* __restrict__ indices) {
    __shared__ double zl[512];
    __shared__ double rv[256];
    __shared__ int ri[256];
    int tid = threadIdx.x;
    int nf = *flagCount;
    if (nf > N_) nf = N_;
    for (int fi = blockIdx.x; fi < nf; fi += gridDim.x) {
        int t = flags[fi];
        int b = t >> 10, p = t & 1023;
        const float* zb = z + (size_t)b * (D_ * P_) + p;
        __syncthreads();
        for (int d = tid; d < 512; d += 256) zl[d] = (double)zb[(size_t)d * P_];
        __syncthreads();
        double bval = 1e300;
        int bidx = 0;
        for (int c = tid * 4; c < tid * 4 + 4; ++c) {
            const float* e = emb + (size_t)c * D_;
            double s = 0.0;
            for (int d = 0; d < 512; ++d) {
                double ed = (double)e[d];
                s += ed * ed - 2.0 * ed * zl[d];
            }
            if (s < bval) { bval = s; bidx = c; }
        }
        rv[tid] = bval; ri[tid] = bidx;
        __syncthreads();
        for (int st = 128; st; st >>= 1) {
            if (tid < st) {
                if (rv[tid + st] < rv[tid] ||
                    (rv[tid + st] == rv[tid] && ri[tid + st] < ri[tid])) {
                    rv[tid] = rv[tid + st]; ri[tid] = ri[tid + st];
                }
            }
            __syncthreads();
        }
        if (tid == 0) indices[t] = ri[0];
        __syncthreads();
    }
}

// ------------------------------------------------------------- k_onehot
__global__ __launch_bounds__(256) void k_onehot(const int* __restrict__ indices,
                                                float* __restrict__ enc,
                                                int* __restrict__ counts) {
    int tid = threadIdx.x;
    int r = blockIdx.x * 8 + (tid >> 5);
    int l = tid & 31;
    int idx = indices[r];
    if (l == 0) atomicAdd(&counts[idx], 1);
    float4* rowp = (float4*)(enc + (size_t)r * K_);
    #pragma unroll
    for (int i = 0; i < 8; ++i) {
        int c4 = i * 32 + l;
        int base = c4 * 4;
        float4 v;
        v.x = (idx == base) ? 1.f : 0.f;
        v.y = (idx == base + 1) ? 1.f : 0.f;
        v.z = (idx == base + 2) ? 1.f : 0.f;
        v.w = (idx == base + 3) ? 1.f : 0.f;
        rowp[c4] = v;
    }
}

// ------------------------------------------------------------- k_gather
__global__ __launch_bounds__(256) void k_gather(const float* __restrict__ z,
                                                const float* __restrict__ emb,
                                                const int* __restrict__ indices,
                                                float* __restrict__ zq,
                                                float* __restrict__ lossp) {
    int tid = threadIdx.x;
    int gid = blockIdx.x * 256 + tid;
    int p4 = gid & 255;
    int rest = gid >> 8;
    int d = rest & 511;
    int b = rest >> 9;
    int p = p4 * 4;
    size_t zoff = (size_t)b * (D_ * P_) + (size_t)d * P_ + p;
    float4 zv = *(const float4*)(z + zoff);
    int nbase = b * P_ + p;
    int i0 = indices[nbase + 0];
    int i1 = indices[nbase + 1];
    int i2 = indices[nbase + 2];
    int i3 = indices[nbase + 3];
    float e0 = emb[(size_t)i0 * D_ + d];
    float e1 = emb[(size_t)i1 * D_ + d];
    float e2 = emb[(size_t)i2 * D_ + d];
    float e3 = emb[(size_t)i3 * D_ + d];
    float d0 = e0 - zv.x;
    float d1 = e1 - zv.y;
    float d2 = e2 - zv.z;
    float d3 = e3 - zv.w;
    float4 o;
    o.x = zv.x + d0; o.y = zv.y + d1; o.z = zv.z + d2; o.w = zv.w + d3;
    *(float4*)(zq + zoff) = o;
    float s = d0 * d0 + d1 * d1 + d2 * d2 + d3 * d3;
    #pragma unroll
    for (int off = 32; off; off >>= 1) s += __shfl_down(s, off, 64);
    __shared__ float wsum[4];
    if ((tid & 63) == 0) wsum[tid >> 6] = s;
    __syncthreads();
    if (tid == 0) lossp[blockIdx.x] = wsum[0] + wsum[1] + wsum[2] + wsum[3];
}

// ------------------------------------------------------------- k_final
__global__ __launch_bounds__(1024) void k_final(const float* __restrict__ lossp,
                                                const int* __restrict__ counts,
                                                float* __restrict__ out_loss,
                                                float* __restrict__ out_perp) {
    int tid = threadIdx.x;
    float s = 0.f;
    for (int i = tid; i < 16384; i += 1024) s += lossp[i];
    #pragma unroll
    for (int off = 32; off; off >>= 1) s += __shfl_down(s, off, 64);
    __shared__ float red[16];
    if ((tid & 63) == 0) red[tid >> 6] = s;

    float pr = (float)counts[tid] * (1.f / 32768.f);
    float term = pr * logf(pr + 1e-10f);
    #pragma unroll
    for (int off = 32; off; off >>= 1) term += __shfl_down(term, off, 64);
    __shared__ float red2[16];
    if ((tid & 63) == 0) red2[tid >> 6] = term;
    __syncthreads();
    if (tid == 0) {
        float tot = 0.f;
        for (int i = 0; i < 16; ++i) tot += red[i];
        *out_loss = 0.25f * (tot / 16777216.f);
        float t2 = 0.f;
        for (int i = 0; i < 16; ++i) t2 += red2[i];
        *out_perp = expf(-t2);
    }
}

// ------------------------------------------------------------- launch
extern "C" void kernel_launch(void* const* d_in, const int* in_sizes, int n_in,
                              void* d_out, int out_size, void* d_ws, size_t ws_size,
                              hipStream_t stream) {
    const float* z   = (const float*)d_in[0];   // [32,512,32,32]
    const float* emb = (const float*)d_in[1];   // [1024,512]

    float* zq       = (float*)d_out;            // 16777216
    float* out_loss = zq + 16777216;
    float* out_perp = zq + 16777217;
    float* enc      = zq + 16777218;            // 33554432 floats

    char* ws = (char*)d_ws;
    float* enorm   = (float*)ws;                          // 4 KB
    int* counts    = (int*)(ws + 4096);                   // 4 KB
    int* flagCount = (int*)(ws + 8192);                   // 4 B
    int* flags     = (int*)(ws + 12288);                  // 128 KB
    int* indices   = (int*)(ws + 12288 + 131072);         // 128 KB
    float* lossp   = (float*)(ws + 12288 + 262144);       // 64 KB

    // big scratch carved from the enc region of d_out (fully consumed before
    // k_onehot overwrites it; rewritten every call -> deterministic).
    char* sb = (char*)d_out + 67108880;
    unsigned short* Xhi  = (unsigned short*)(sb);                   // 33.5 MB
    unsigned short* Xlo  = (unsigned short*)(sb + 33554432);        // 33.5 MB
    unsigned short* EhiP = (unsigned short*)(sb + 67108864);        // 1 MB
    unsigned short* EloP = (unsigned short*)(sb + 68157440);        // 1 MB
    u64* part = (u64*)(sb + 69206016);                              // 4 MB

    k_prepE<<<K_, 128, 0, stream>>>(emb, EhiP, EloP, enorm, counts, flagCount);
    k_prep<<<256, 256, 0, stream>>>(z, Xhi, Xlo);
    k_gemm<<<512, 512, 0, stream>>>(Xhi, Xlo, EhiP, EloP, enorm, part);
    k_merge<<<128, 256, 0, stream>>>(part, indices, flags, flagCount);
    k_repair<<<256, 256, 0, stream>>>(z, emb, flags, flagCount, indices);
    k_onehot<<<4096, 256, 0, stream>>>(indices, enc, counts);
    k_gather<<<16384, 256, 0, stream>>>(z, emb, indices, zq, lossp);
    k_final<<<1, 1024, 0, stream>>>(lossp, counts, out_loss, out_perp);
}